// Round 1
// 314.871 us; speedup vs baseline: 1.0051x; 1.0051x over previous
//
#include <hip/hip_runtime.h>
#include <math.h>

#define N_NODES 2048
#define NNE ((long)N_NODES * N_NODES)   // elems per channel matrix
#define NNE4 (NNE / 4)

// f16 two-term split: x ~= h + l (true residual). Three MFMA products
// (hh, lh, hl) into ONE fp32 accumulator; dropped l*l term ~2^-22 relative.
// Scale chain (all powers of 2, exact):
//   V0' = supd * 2^13                       (typ ~2, residuals normal)
//   T0  = Hc@V0'  -> scaled by sT0[f] = 2^(10-ilogb(cn0[f])), cn0=sum_m|V0'|
//   T1  = Hb@T0'  -> scaled by sT1[f] = 2^(10-ilogb(cn1[f])), cn1=sum_j|T0'|
//   T2  = Ha@T1'  (fp32); out = d*(T2*2^(i0+i1-33) + supd) + b
#define SUPD_SCALE 8192.0f

typedef _Float16 half4_t __attribute__((ext_vector_type(4)));
typedef _Float16 half8_t __attribute__((ext_vector_type(8)));
typedef float    floatx4 __attribute__((ext_vector_type(4)));

__device__ __forceinline__ void async_cp16(const void* g, void* l) {
  __builtin_amdgcn_global_load_lds((const __attribute__((address_space(1))) void*)g,
                                   (__attribute__((address_space(3))) void*)l,
                                   16, 0, 0);
}

__device__ __forceinline__ float colscale_from(float cn) {
  return exp2f((float)(10 - ilogbf(fmaxf(cn, 1e-37f))));
}

// ---- softmax of the three 4x4 weight matrices + zero rs (basis rowsums)
// ---- and cn0/cn1. grid 16 x 256: 4096 threads zero 8192 floats of rs.
__global__ void softmax3_zero_k(const float* __restrict__ w1,
                                const float* __restrict__ w2,
                                const float* __restrict__ w3,
                                float* __restrict__ fw,
                                float* __restrict__ rs,
                                float* __restrict__ cn, int cncnt) {
  int g = blockIdx.x * 256 + threadIdx.x;
  ((float2*)rs)[g] = make_float2(0.f, 0.f);      // rs: 4*2048 floats
  if (g < cncnt) cn[g] = 0.f;                    // cn0+cn1
  if (blockIdx.x == 0 && threadIdx.x < 12) {
    int t = threadIdx.x;
    const float* src = (t < 4) ? w1 : (t < 8) ? w2 : w3;
    int r = t & 3;
    float v0 = src[r * 4 + 0], v1 = src[r * 4 + 1];
    float v2 = src[r * 4 + 2], v3 = src[r * 4 + 3];
    float m = fmaxf(fmaxf(v0, v1), fmaxf(v2, v3));
    float e0 = expf(v0 - m), e1 = expf(v1 - m), e2 = expf(v2 - m), e3 = expf(v3 - m);
    float inv = 1.0f / (e0 + e1 + e2 + e3);
    fw[t * 4 + 0] = e0 * inv; fw[t * 4 + 1] = e1 * inv;
    fw[t * 4 + 2] = e2 * inv; fw[t * 4 + 3] = e3 * inv;
  }
}

// ---------------- support = X @ gcn_w  [2048,256]@[256,128] ----------------
__global__ __launch_bounds__(128)
void support_k(const float* __restrict__ X, const float* __restrict__ W,
               float* __restrict__ sup) {
  __shared__ float Xs[256];
  const int t = threadIdx.x;
  const int m = blockIdx.x;
  Xs[t]       = X[(long)m * 256 + t];
  Xs[t + 128] = X[(long)m * 256 + t + 128];
  __syncthreads();
  float acc = 0.f;
  #pragma unroll 8
  for (int k = 0; k < 256; ++k) acc = fmaf(Xs[k], W[(long)k * 128 + t], acc);
  sup[(long)m * 128 + t] = acc;
}

// -- one A pass -> Ha, Hb, Hc split row-major; rowsums rs[e][r] by-product --
__global__ __launch_bounds__(256)
void mix3_k(const float4* __restrict__ A4, const float* __restrict__ fw,
            _Float16* __restrict__ HaH, _Float16* __restrict__ HaL,
            _Float16* __restrict__ HbH, _Float16* __restrict__ HbL,
            _Float16* __restrict__ HcH, _Float16* __restrict__ HcL,
            float* __restrict__ rs, int c0, int nc, int do_rs) {
  long idx = (long)blockIdx.x * 256 + threadIdx.x;
  float4 a0 = A4[idx];
  float4 a1 = A4[NNE4 + idx];
  float4 a2 = A4[2 * NNE4 + idx];
  float4 a3 = A4[3 * NNE4 + idx];
  for (int ci = 0; ci < nc; ++ci) {
    _Float16* OH[3] = {HaH, HbH, HcH};
    _Float16* OL[3] = {HaL, HbL, HcL};
    #pragma unroll
    for (int s = 0; s < 3; ++s) {
      const float* wv = fw + s * 16 + (c0 + ci) * 4;
      float o[4];
      o[0] = wv[0] * a0.x + wv[1] * a1.x + wv[2] * a2.x + wv[3] * a3.x;
      o[1] = wv[0] * a0.y + wv[1] * a1.y + wv[2] * a2.y + wv[3] * a3.y;
      o[2] = wv[0] * a0.z + wv[1] * a1.z + wv[2] * a2.z + wv[3] * a3.z;
      o[3] = wv[0] * a0.w + wv[1] * a1.w + wv[2] * a2.w + wv[3] * a3.w;
      half4_t h, l;
      #pragma unroll
      for (int d = 0; d < 4; ++d) {
        _Float16 hh = (_Float16)o[d];
        h[d] = hh;
        l[d] = (_Float16)(o[d] - (float)hh);
      }
      *(half4_t*)(OH[s] + (long)ci * NNE + 4 * idx) = h;
      *(half4_t*)(OL[s] + (long)ci * NNE + 4 * idx) = l;
    }
  }
  if (do_rs) {
    // block covers 1024 contiguous floats = half of row r (same row for all e)
    __shared__ float red[4][4];
    float s[4];
    s[0] = (a0.x + a0.y) + (a0.z + a0.w);
    s[1] = (a1.x + a1.y) + (a1.z + a1.w);
    s[2] = (a2.x + a2.y) + (a2.z + a2.w);
    s[3] = (a3.x + a3.y) + (a3.z + a3.w);
    #pragma unroll
    for (int o = 32; o > 0; o >>= 1) {
      #pragma unroll
      for (int e = 0; e < 4; ++e) s[e] += __shfl_down(s[e], o, 64);
    }
    const int lane = threadIdx.x & 63, wv = threadIdx.x >> 6;
    if (lane == 0) {
      #pragma unroll
      for (int e = 0; e < 4; ++e) red[wv][e] = s[e];
    }
    __syncthreads();
    if (threadIdx.x < 4) {
      int e = threadIdx.x;
      float tot = (red[0][e] + red[1][e]) + (red[2][e] + red[3][e]);
      atomicAdd(&rs[(long)e * N_NODES + (blockIdx.x >> 1)], tot);
    }
  }
}

// -- vout[c][r] = sum_e fw[off+c*4+e] * (A_e @ vin'[c])[r]  (fp32, one A pass)
// -- if mixoff >= 0: vin is rs[e][j]; vin'[c][j] = sum_e fw[mixoff+c*4+e]*rs[e][j]
__global__ __launch_bounds__(256)
void matvecA_k(const float* __restrict__ A, const float* __restrict__ fw, int off,
               const float* __restrict__ vin, float* __restrict__ vout, int mixoff) {
  __shared__ float vs[4 * 2048];
  const int t = threadIdx.x;
  if (mixoff < 0) {
    for (int i = t; i < 4 * 2048; i += 256) vs[i] = vin[i];
  } else {
    for (int i = t; i < 4 * 2048; i += 256) {
      int c = i >> 11, j = i & 2047;
      const float* wv = fw + mixoff + c * 4;
      vs[i] = wv[0] * vin[j] + wv[1] * vin[2048 + j] +
              wv[2] * vin[2 * 2048 + j] + wv[3] * vin[3 * 2048 + j];
    }
  }
  __syncthreads();
  const int wave = t >> 6, lane = t & 63;
  const int r = blockIdx.x * 4 + wave;
  float acc[4][4] = {{0.f}};
  #pragma unroll
  for (int e = 0; e < 4; ++e) {
    const float4* row = (const float4*)(A + (long)e * NNE + (long)r * N_NODES);
    for (int j4 = lane; j4 < 512; j4 += 64) {
      float4 a = row[j4];
      #pragma unroll
      for (int c = 0; c < 4; ++c) {
        const float4 v = *(const float4*)&vs[c * 2048 + j4 * 4];
        acc[e][c] += (a.x * v.x + a.y * v.y) + (a.z * v.z + a.w * v.w);
      }
    }
  }
  #pragma unroll
  for (int e = 0; e < 4; ++e)
    #pragma unroll
    for (int c = 0; c < 4; ++c)
      for (int o = 32; o > 0; o >>= 1) acc[e][c] += __shfl_down(acc[e][c], o, 64);
  if (lane == 0) {
    #pragma unroll
    for (int c = 0; c < 4; ++c) {
      float s = fw[off + c * 4 + 0] * acc[0][c] + fw[off + c * 4 + 1] * acc[1][c] +
                fw[off + c * 4 + 2] * acc[2][c] + fw[off + c * 4 + 3] * acc[3][c];
      vout[c * N_NODES + r] = s;
    }
  }
}

// -- fused: dm = 1/sqrt(1+deg); supd = dm*sup (side output, + dvec);
// -- VT[z][f][m] = split( supd*2^13 ); cn0[z][f] += sum_m |val| ------------
__global__ __launch_bounds__(256)
void transposeV_k(const float* __restrict__ sup, const float* __restrict__ deg,
                  float* __restrict__ dvec, float* __restrict__ supd,
                  _Float16* __restrict__ TH, _Float16* __restrict__ TL,
                  float* __restrict__ cn0, int c0) {
  __shared__ _Float16 sh[32][33], sl[32][33];
  __shared__ float red[8][32];
  const int t = threadIdx.x;
  const int z = blockIdx.z;
  const int c = c0 + z;
  const int m0 = blockIdx.x * 32, f0 = blockIdx.y * 32;
  const int r0 = t >> 5, col = t & 31;
  float part = 0.f;
  #pragma unroll
  for (int m = 0; m < 4; ++m) {
    const int row = m0 + r0 + 8 * m;
    float dm = 1.0f / sqrtf(1.0f + deg[(long)c * N_NODES + row]);
    float sv = sup[(long)row * 128 + f0 + col] * dm;
    supd[((long)z * N_NODES + row) * 128 + f0 + col] = sv;
    if (blockIdx.y == 0 && col == 0) dvec[(long)c * N_NODES + row] = dm;
    float v = sv * SUPD_SCALE;
    _Float16 h = (_Float16)v;
    sh[r0 + 8 * m][col] = h;
    sl[r0 + 8 * m][col] = (_Float16)(v - (float)h);
    part += fabsf(v);
  }
  red[r0][col] = part;
  __syncthreads();
  if (t < 32) {
    float s = 0.f;
    #pragma unroll
    for (int q = 0; q < 8; ++q) s += red[q][t];
    atomicAdd(&cn0[(long)z * 128 + f0 + t], s);
  }
  const int rr = t >> 3, cq = (t & 7) * 4;
  half4_t oh, ol;
  #pragma unroll
  for (int d = 0; d < 4; ++d) { oh[d] = sh[cq + d][rr]; ol[d] = sl[cq + d][rr]; }
  long ob = (long)z * 128 * N_NODES + (long)(f0 + rr) * N_NODES + m0 + cq;
  *(half4_t*)(TH + ob) = oh;
  *(half4_t*)(TL + ob) = ol;
}

// ---- thin split-f16 GEMM, split-K: partials[kc][z][i][f] = A[z]@B[z] ------
// A [z][2048][2048] split halves; B [z][128][2048] split halves (NT).
// i-tile 64 rows -> grid (4 kc, 32 i, z): 512 blocks, 48 KB LDS, 2 blocks/CU.
__global__ __launch_bounds__(256, 2)
void gemm_thin_k(const _Float16* __restrict__ AH, const _Float16* __restrict__ AL,
                 const _Float16* __restrict__ BH, const _Float16* __restrict__ BL,
                 float* __restrict__ C) {
  // per buffer (halfs): Ah[0,2048) Al[2048,4096) Bh[4096,8192) Bl[8192,12288)
  __shared__ __align__(16) _Float16 smem[2][12288];

  const int t = threadIdx.x;
  const int lane = t & 63;
  const int w = t >> 6;
  const int wm = w >> 1, wn = w & 1;
  const int i0 = blockIdx.y * 64;
  const int koff = blockIdx.x * 512;
  const int z = blockIdx.z;
  const long zoA = (long)z * NNE;
  const long zoB = (long)z * 128 * N_NODES;

  // stage swizzle: physical k-chunk p=lane&3 holds logical chunk (p-(r16>>1))&3
  const int kc_st = (((lane & 3) - ((lane >> 3) & 3)) & 3) * 8;
  const long rowk = (long)(lane >> 2) * N_NODES + koff + kc_st;

  const _Float16* gp0;
  const _Float16* gp1;
  int d0 = 0;
  if (w == 0) {            // A: 64 rows h + l, 4 q-groups each
    gp0 = AH + zoA + (long)i0 * N_NODES + rowk;
    gp1 = AL + zoA + (long)i0 * N_NODES + rowk;
  } else if (w == 1) {     // Bh: 128 f-rows, 8 q-groups
    gp0 = BH + zoB + rowk; gp1 = gp0; d0 = 4096;
  } else if (w == 2) {     // Bl
    gp0 = BL + zoB + rowk; gp1 = gp0; d0 = 8192;
  } else {                 // w3: no staging role
    gp0 = AH; gp1 = AH;
  }

  auto stage = [&](_Float16* lb) {
    if (w == 0) {
      #pragma unroll
      for (int q = 0; q < 4; ++q) {
        async_cp16(gp0 + q * (16L * N_NODES), lb + 0    + q * 512 + lane * 8);
        async_cp16(gp1 + q * (16L * N_NODES), lb + 2048 + q * 512 + lane * 8);
      }
    } else if (w < 3) {
      #pragma unroll
      for (int q = 0; q < 8; ++q)
        async_cp16(gp0 + q * (16L * N_NODES), lb + d0 + q * 512 + lane * 8);
    }
    gp0 += 32; gp1 += 32;
  };

  const int fr = lane & 15;
  const int fkz = (((lane >> 4) + (fr >> 1)) & 3) * 8;
  const int aoff = (wm * 32 + fr) * 32 + fkz;
  const int boff = (wn * 64 + fr) * 32 + fkz;

  floatx4 acc[2][4];
  #pragma unroll
  for (int i = 0; i < 2; ++i)
    #pragma unroll
    for (int j = 0; j < 4; ++j) {
      floatx4 zz = {0.f, 0.f, 0.f, 0.f};
      acc[i][j] = zz;
    }

  stage(&smem[0][0]);
  __syncthreads();

  const int NKI = 512 / 32;
  for (int kt = 0; kt < NKI; ++kt) {
    const int p = kt & 1;
    if (kt + 1 < NKI) stage(&smem[p ^ 1][0]);
    const _Float16* base = &smem[p][0];
    half8_t ah[2], al[2], bh[4], bl[4];
    #pragma unroll
    for (int mt = 0; mt < 2; ++mt) {
      ah[mt] = *(const half8_t*)(base + aoff + mt * 512);
      al[mt] = *(const half8_t*)(base + 2048 + aoff + mt * 512);
    }
    #pragma unroll
    for (int nt = 0; nt < 4; ++nt) {
      bh[nt] = *(const half8_t*)(base + 4096 + boff + nt * 512);
      bl[nt] = *(const half8_t*)(base + 8192 + boff + nt * 512);
    }
    #pragma unroll
    for (int mt = 0; mt < 2; ++mt)
      #pragma unroll
      for (int nt = 0; nt < 4; ++nt) {
        acc[mt][nt] = __builtin_amdgcn_mfma_f32_16x16x32_f16(ah[mt], bh[nt], acc[mt][nt], 0, 0, 0);
        acc[mt][nt] = __builtin_amdgcn_mfma_f32_16x16x32_f16(al[mt], bh[nt], acc[mt][nt], 0, 0, 0);
        acc[mt][nt] = __builtin_amdgcn_mfma_f32_16x16x32_f16(ah[mt], bl[nt], acc[mt][nt], 0, 0, 0);
      }
    __syncthreads();
  }

  const int er = (lane >> 4) * 4;
  const int ec = lane & 15;
  float* Cb = C + ((long)(blockIdx.x * gridDim.z + z) * N_NODES + i0) * 128;
  #pragma unroll
  for (int mt = 0; mt < 2; ++mt)
    #pragma unroll
    for (int nt = 0; nt < 4; ++nt) {
      const int f = wn * 64 + nt * 16 + ec;
      #pragma unroll
      for (int r = 0; r < 4; ++r)
        Cb[(long)(wm * 32 + mt * 16 + er + r) * 128 + f] = acc[mt][nt][r];
    }
}

// -- T'[z][f][j] = split( (sum_kc P[kc][z][j][f]) * s(cn_in[z][f]) ) --------
__global__ __launch_bounds__(256)
void combineT_k(const float* __restrict__ P, int nc,
                const float* __restrict__ cn_in, float* __restrict__ cn_out,
                _Float16* __restrict__ TH, _Float16* __restrict__ TL) {
  __shared__ _Float16 sh[32][33], sl[32][33];
  __shared__ float red[8][32];
  const int t = threadIdx.x;
  const int z = blockIdx.z;
  const int j0 = blockIdx.x * 32, f0 = blockIdx.y * 32;
  const int r0 = t >> 5, col = t & 31;
  const float s = colscale_from(cn_in[(long)z * 128 + f0 + col]);
  const long step = (long)nc * N_NODES * 128;
  float part = 0.f;
  #pragma unroll
  for (int m = 0; m < 4; ++m) {
    long idx = ((long)z * N_NODES + j0 + r0 + 8 * m) * 128 + f0 + col;
    float v = ((P[idx] + P[idx + step]) + (P[idx + 2 * step] + P[idx + 3 * step])) * s;
    _Float16 h = (_Float16)v;
    sh[r0 + 8 * m][col] = h;
    sl[r0 + 8 * m][col] = (_Float16)(v - (float)h);
    part += fabsf(v);
  }
  if (cn_out) red[r0][col] = part;
  __syncthreads();
  if (cn_out && t < 32) {
    float ss = 0.f;
    #pragma unroll
    for (int q = 0; q < 8; ++q) ss += red[q][t];
    atomicAdd(&cn_out[(long)z * 128 + f0 + t], ss);
  }
  const int rr = t >> 3, cq = (t & 7) * 4;
  half4_t oh, ol;
  #pragma unroll
  for (int d = 0; d < 4; ++d) { oh[d] = sh[cq + d][rr]; ol[d] = sl[cq + d][rr]; }
  long ob = (long)z * 128 * N_NODES + (long)(f0 + rr) * N_NODES + j0 + cq;
  *(half4_t*)(TH + ob) = oh;
  *(half4_t*)(TL + ob) = ol;
}

// --- out[i][c*128+f] = relu( d*( T2sum * 2^(i0+i1-33) + supd ) + b ) -------
__global__ __launch_bounds__(256)
void final_k(const float4* __restrict__ T2, const float4* __restrict__ supd,
             const float* __restrict__ dvec, const float* __restrict__ cn0,
             const float* __restrict__ cn1, const float* __restrict__ bias,
             float* __restrict__ out, int c0, int nc) {
  const int t = threadIdx.x;
  const int z = blockIdx.y;
  const int c = c0 + z;
  const int idx = blockIdx.x * 256 + t;
  const int i = idx >> 5;
  const int fq = (idx & 31) * 4;
  const long step4 = (long)nc * N_NODES * 32;
  long b4 = (long)z * N_NODES * 32 + idx;
  float4 s0 = T2[b4];
  float4 s1 = T2[b4 + step4];
  float4 s2 = T2[b4 + 2 * step4];
  float4 s3 = T2[b4 + 3 * step4];
  float4 sp = supd[(long)z * N_NODES * 32 + idx];
  const float dn = dvec[(long)c * N_NODES + i];
  float inv[4];
  #pragma unroll
  for (int d = 0; d < 4; ++d) {
    int i0 = ilogbf(fmaxf(cn0[(long)z * 128 + fq + d], 1e-37f));
    int i1 = ilogbf(fmaxf(cn1[(long)z * 128 + fq + d], 1e-37f));
    inv[d] = exp2f((float)(i0 + i1 - 33));
  }
  float4 o;
  o.x = fmaxf(dn * (((s0.x + s1.x) + (s2.x + s3.x)) * inv[0] + sp.x) + bias[fq + 0], 0.f);
  o.y = fmaxf(dn * (((s0.y + s1.y) + (s2.y + s3.y)) * inv[1] + sp.y) + bias[fq + 1], 0.f);
  o.z = fmaxf(dn * (((s0.z + s1.z) + (s2.z + s3.z)) * inv[2] + sp.z) + bias[fq + 2], 0.f);
  o.w = fmaxf(dn * (((s0.w + s1.w) + (s2.w + s3.w)) * inv[3] + sp.w) + bias[fq + 3], 0.f);
  *(float4*)(out + (long)i * 512 + c * 128 + fq) = o;
}

extern "C" void kernel_launch(void* const* d_in, const int* in_sizes, int n_in,
                              void* d_out, int out_size, void* d_ws, size_t ws_size,
                              hipStream_t stream) {
  const float* A  = (const float*)d_in[0];
  const float* X  = (const float*)d_in[1];
  const float* w1 = (const float*)d_in[2];
  const float* w2 = (const float*)d_in[3];
  const float* w3 = (const float*)d_in[4];
  const float* gw = (const float*)d_in[5];
  const float* gb = (const float*)d_in[6];
  float* out = (float*)d_out;

  // ---- workspace layout (floats first, then f16 arena; all 16B aligned) ----
  float* ws   = (float*)d_ws;
  float* fw   = ws;                        // 64
  float* rs   = fw + 64;                   // 4*2048 (basis rowsums of A_e)
  float* v1   = rs + 4 * N_NODES;          // 4*2048
  float* deg  = v1 + 4 * N_NODES;          // 4*2048
  float* dvec = deg + 4 * N_NODES;         // 4*2048
  float* sup  = dvec + 4 * N_NODES;        // 2048*128
  float* dyn  = sup + (long)N_NODES * 128;

  const long fixed_f = 64 + 16 * N_NODES + (long)N_NODES * 128;
  const long per_f32 = 5L * N_NODES * 128 + 256;          // supd + 4x partials + cn0/cn1
  const long per_f16 = 6L * NNE + 6L * 128 * N_NODES;     // 3 split matrices + 3 split thin
  auto need = [&](int nc) {
    return (fixed_f + (long)nc * per_f32) * 4 + (long)nc * per_f16 * 2;
  };
  int nc = 1;
  if ((long)ws_size >= need(4)) nc = 4;
  else if ((long)ws_size >= need(2)) nc = 2;

  float* cn0  = dyn;                                   // [nc][128]
  float* cn1  = cn0 + (long)nc * 128;                  // [nc][128]
  float* supd = cn1 + (long)nc * 128;                  // [nc][2048][128]
  float* Mtmp = supd + (long)nc * N_NODES * 128;       // [4][nc][2048][128]
  _Float16* arena = (_Float16*)(Mtmp + 4L * nc * N_NODES * 128);
  _Float16* HaH = arena;
  _Float16* HaL = HaH + (long)nc * NNE;
  _Float16* HbH = HaL + (long)nc * NNE;
  _Float16* HbL = HbH + (long)nc * NNE;
  _Float16* HcH = HbL + (long)nc * NNE;
  _Float16* HcL = HcH + (long)nc * NNE;
  _Float16* VTH = HcL + (long)nc * NNE;                // [nc][128][2048]
  _Float16* VTL = VTH + (long)nc * 128 * N_NODES;
  _Float16* T0H = VTL + (long)nc * 128 * N_NODES;
  _Float16* T0L = T0H + (long)nc * 128 * N_NODES;
  _Float16* T1H = T0L + (long)nc * 128 * N_NODES;
  _Float16* T1L = T1H + (long)nc * 128 * N_NODES;

  // ---- channel-independent prework ----
  softmax3_zero_k<<<16, 256, 0, stream>>>(w1, w2, w3, fw, rs, cn0, 2 * nc * 128);
  support_k<<<N_NODES, 128, 0, stream>>>(X, gw, sup);

  for (int c0 = 0; c0 < 4; c0 += nc) {
    if (c0 > 0) hipMemsetAsync(cn0, 0, 2L * nc * 128 * sizeof(float), stream);
    // Ha/Hb/Hc split row-major, one A pass; rs = basis rowsums (first iter)
    mix3_k<<<(int)(NNE4 / 256), 256, 0, stream>>>((const float4*)A, fw,
                                                  HaH, HaL, HbH, HbL, HcH, HcL,
                                                  rs, c0, nc, c0 == 0 ? 1 : 0);
    if (c0 == 0) {
      // v1 = Hb @ (fw3-mix of rs) ; deg = Ha @ v1   (channel-independent)
      matvecA_k<<<N_NODES / 4, 256, 0, stream>>>(A, fw, 16, rs, v1, 32);
      matvecA_k<<<N_NODES / 4, 256, 0, stream>>>(A, fw, 0, v1, deg, -1);
    }
    // fused: supd = d .* support ; VT = (supd*2^13)^T split ; cn0 col 1-norms
    transposeV_k<<<dim3(64, 4, nc), 256, 0, stream>>>(sup, deg, dvec, supd,
                                                      VTH, VTL, cn0, c0);
    // T0 = Hc @ VT
    gemm_thin_k<<<dim3(4, 32, nc), 256, 0, stream>>>(HcH, HcL, VTH, VTL, Mtmp);
    combineT_k<<<dim3(64, 4, nc), 256, 0, stream>>>(Mtmp, nc, cn0, cn1, T0H, T0L);
    // T1 = Hb @ T0'
    gemm_thin_k<<<dim3(4, 32, nc), 256, 0, stream>>>(HbH, HbL, T0H, T0L, Mtmp);
    combineT_k<<<dim3(64, 4, nc), 256, 0, stream>>>(Mtmp, nc, cn1, nullptr, T1H, T1L);
    // T2 = Ha @ T1'  (fp32 partials)
    gemm_thin_k<<<dim3(4, 32, nc), 256, 0, stream>>>(HaH, HaL, T1H, T1L, Mtmp);
    // out = relu( d*(T2*inv + supd) + b )
    final_k<<<dim3(256, nc), 256, 0, stream>>>((const float4*)Mtmp,
                                               (const float4*)supd, dvec,
                                               cn0, cn1, gb, out, c0, nc);
  }
}

// Round 2
// 274.911 us; speedup vs baseline: 1.1512x; 1.1454x over previous
//
#include <hip/hip_runtime.h>
#include <math.h>

#define N_NODES 2048
#define NNE ((long)N_NODES * N_NODES)   // elems per channel matrix

// f16 two-term split: x ~= h + l (true residual). Three MFMA products
// (hh, lh, hl) into ONE fp32 accumulator; dropped l*l term ~2^-22 relative.
// Scale chain (all powers of 2, exact):
//   V0' = supd * 2^13
//   T0  = Hc@V0'  -> scaled by sT0[f] = 2^(10-ilogb(cn0[f])), cn0=sum_m|V0'|
//   T1  = Hb@T0'  -> scaled by sT1[f] = 2^(10-ilogb(cn1[f])), cn1=sum_j|T0'|
//   T2  = Ha@T1'  (fp32); out = d*(T2*2^(i0+i1-33) + supd) + b
// NEW this round: H matrices are never materialized — gemm_mix_k mixes
// A -> H[z] on the fly (fp32 regs -> f16 split -> LDS) inside each stage.
#define SUPD_SCALE 8192.0f

typedef _Float16 half4_t __attribute__((ext_vector_type(4)));
typedef _Float16 half8_t __attribute__((ext_vector_type(8)));
typedef float    floatx4 __attribute__((ext_vector_type(4)));

__device__ __forceinline__ void async_cp16(const void* g, void* l) {
  __builtin_amdgcn_global_load_lds((const __attribute__((address_space(1))) void*)g,
                                   (__attribute__((address_space(3))) void*)l,
                                   16, 0, 0);
}

__device__ __forceinline__ float colscale_from(float cn) {
  return exp2f((float)(10 - ilogbf(fmaxf(cn, 1e-37f))));
}

// ---- softmax of the three 4x4 weight matrices + zero cn0/cn1 (1024 f) ----
__global__ void softmax3_zero_k(const float* __restrict__ w1,
                                const float* __restrict__ w2,
                                const float* __restrict__ w3,
                                float* __restrict__ fw,
                                float* __restrict__ cn) {
  int t = threadIdx.x;
  float4 z4 = {0.f, 0.f, 0.f, 0.f};
  ((float4*)cn)[t] = z4;                       // 256*4 = 1024 floats
  if (t < 12) {
    const float* src = (t < 4) ? w1 : (t < 8) ? w2 : w3;
    int r = t & 3;
    float v0 = src[r * 4 + 0], v1 = src[r * 4 + 1];
    float v2 = src[r * 4 + 2], v3 = src[r * 4 + 3];
    float m = fmaxf(fmaxf(v0, v1), fmaxf(v2, v3));
    float e0 = expf(v0 - m), e1 = expf(v1 - m), e2 = expf(v2 - m), e3 = expf(v3 - m);
    float inv = 1.0f / (e0 + e1 + e2 + e3);
    fw[t * 4 + 0] = e0 * inv; fw[t * 4 + 1] = e1 * inv;
    fw[t * 4 + 2] = e2 * inv; fw[t * 4 + 3] = e3 * inv;
  }
}

// ---------------- support = X @ gcn_w  [2048,256]@[256,128] ----------------
__global__ __launch_bounds__(128)
void support_k(const float* __restrict__ X, const float* __restrict__ W,
               float* __restrict__ sup) {
  __shared__ float Xs[256];
  const int t = threadIdx.x;
  const int m = blockIdx.x;
  Xs[t]       = X[(long)m * 256 + t];
  Xs[t + 128] = X[(long)m * 256 + t + 128];
  __syncthreads();
  float acc = 0.f;
  #pragma unroll 8
  for (int k = 0; k < 256; ++k) acc = fmaf(Xs[k], W[(long)k * 128 + t], acc);
  sup[(long)m * 128 + t] = acc;
}

// ---- rc[c][r] = sum_e fw3[c][e] * rowsum(A_e)[r]   (one A pass) ----------
__global__ __launch_bounds__(256)
void rc_from_A_k(const float* __restrict__ A, const float* __restrict__ fw,
                 float* __restrict__ rc) {
  const int wave = threadIdx.x >> 6, lane = threadIdx.x & 63;
  const int r = blockIdx.x * 4 + wave;
  float se[4];
  #pragma unroll
  for (int e = 0; e < 4; ++e) {
    const float4* row = (const float4*)(A + (long)e * NNE + (long)r * N_NODES);
    float s = 0.f;
    for (int j4 = lane; j4 < 512; j4 += 64) {
      float4 a = row[j4];
      s += (a.x + a.y) + (a.z + a.w);
    }
    for (int o = 32; o > 0; o >>= 1) s += __shfl_down(s, o, 64);
    se[e] = s;
  }
  if (lane == 0) {
    #pragma unroll
    for (int c = 0; c < 4; ++c)
      rc[c * N_NODES + r] = fw[32 + c * 4 + 0] * se[0] + fw[32 + c * 4 + 1] * se[1] +
                            fw[32 + c * 4 + 2] * se[2] + fw[32 + c * 4 + 3] * se[3];
  }
}

// -- vout[c][r] = sum_e fw[off+c*4+e] * (A_e @ vin[c])[r]  (fp32, one A pass)
__global__ __launch_bounds__(256)
void matvecA_k(const float* __restrict__ A, const float* __restrict__ fw, int off,
               const float* __restrict__ vin, float* __restrict__ vout) {
  __shared__ float vs[4 * 2048];
  const int t = threadIdx.x;
  for (int i = t; i < 4 * 2048; i += 256) vs[i] = vin[i];
  __syncthreads();
  const int wave = t >> 6, lane = t & 63;
  const int r = blockIdx.x * 4 + wave;
  float acc[4][4] = {{0.f}};
  #pragma unroll
  for (int e = 0; e < 4; ++e) {
    const float4* row = (const float4*)(A + (long)e * NNE + (long)r * N_NODES);
    for (int j4 = lane; j4 < 512; j4 += 64) {
      float4 a = row[j4];
      #pragma unroll
      for (int c = 0; c < 4; ++c) {
        const float4 v = *(const float4*)&vs[c * 2048 + j4 * 4];
        acc[e][c] += (a.x * v.x + a.y * v.y) + (a.z * v.z + a.w * v.w);
      }
    }
  }
  #pragma unroll
  for (int e = 0; e < 4; ++e)
    #pragma unroll
    for (int c = 0; c < 4; ++c)
      for (int o = 32; o > 0; o >>= 1) acc[e][c] += __shfl_down(acc[e][c], o, 64);
  if (lane == 0) {
    #pragma unroll
    for (int c = 0; c < 4; ++c) {
      float s = fw[off + c * 4 + 0] * acc[0][c] + fw[off + c * 4 + 1] * acc[1][c] +
                fw[off + c * 4 + 2] * acc[2][c] + fw[off + c * 4 + 3] * acc[3][c];
      vout[c * N_NODES + r] = s;
    }
  }
}

// -- fused: dm = 1/sqrt(1+deg); supd = dm*sup (side output, + dvec);
// -- VT[z][f][m] = split( supd*2^13 ); cn0[z][f] += sum_m |val| ------------
__global__ __launch_bounds__(256)
void transposeV_k(const float* __restrict__ sup, const float* __restrict__ deg,
                  float* __restrict__ dvec, float* __restrict__ supd,
                  _Float16* __restrict__ TH, _Float16* __restrict__ TL,
                  float* __restrict__ cn0) {
  __shared__ _Float16 sh[32][33], sl[32][33];
  __shared__ float red[8][32];
  const int t = threadIdx.x;
  const int z = blockIdx.z;
  const int m0 = blockIdx.x * 32, f0 = blockIdx.y * 32;
  const int r0 = t >> 5, col = t & 31;
  float part = 0.f;
  #pragma unroll
  for (int m = 0; m < 4; ++m) {
    const int row = m0 + r0 + 8 * m;
    float dm = 1.0f / sqrtf(1.0f + deg[(long)z * N_NODES + row]);
    float sv = sup[(long)row * 128 + f0 + col] * dm;
    supd[((long)z * N_NODES + row) * 128 + f0 + col] = sv;
    if (blockIdx.y == 0 && col == 0) dvec[(long)z * N_NODES + row] = dm;
    float v = sv * SUPD_SCALE;
    _Float16 h = (_Float16)v;
    sh[r0 + 8 * m][col] = h;
    sl[r0 + 8 * m][col] = (_Float16)(v - (float)h);
    part += fabsf(v);
  }
  red[r0][col] = part;
  __syncthreads();
  if (t < 32) {
    float s = 0.f;
    #pragma unroll
    for (int q = 0; q < 8; ++q) s += red[q][t];
    atomicAdd(&cn0[(long)z * 128 + f0 + t], s);
  }
  const int rr = t >> 3, cq = (t & 7) * 4;
  half4_t oh, ol;
  #pragma unroll
  for (int d = 0; d < 4; ++d) { oh[d] = sh[cq + d][rr]; ol[d] = sl[cq + d][rr]; }
  long ob = (long)z * 128 * N_NODES + (long)(f0 + rr) * N_NODES + m0 + cq;
  *(half4_t*)(TH + ob) = oh;
  *(half4_t*)(TL + ob) = ol;
}

// ---- fused mix+GEMM: partials[kc][ch][i][f] = (sum_e fw[off+ch*4+e] A_e) @ B[ch]
// A fp32 staged per-thread -> mixed+split to f16 in regs -> LDS -> MFMA.
// grid (zz 2, i-tiles 64, kc 4); block 256 (4 waves); 40 KB LDS -> 4 blk/CU.
__global__ __launch_bounds__(256, 4)
void gemm_mix_k(const float* __restrict__ A, const float* __restrict__ fw, int off,
                const _Float16* __restrict__ BH, const _Float16* __restrict__ BL,
                float* __restrict__ C) {
  // Hs planes: [cl*2+hl][r*32 + swz] (32 r x 32 k each). Bs: [cl*2+hl][f*32 + swz]
  __shared__ __align__(16) _Float16 Hs[4][1024];
  __shared__ __align__(16) _Float16 Bs[4][4096];

  const int t = threadIdx.x;
  const int lane = t & 63;
  const int w = t >> 6;
  const int zz = blockIdx.x;            // channel pair
  const int i0 = blockIdx.y * 32;
  const int koff = blockIdx.z * 512;

  // per-pair softmax weights (uniform -> SGPR)
  float wv0[4], wv1[4];
  #pragma unroll
  for (int e = 0; e < 4; ++e) {
    wv0[e] = fw[off + (zz * 2 + 0) * 4 + e];
    wv1[e] = fw[off + (zz * 2 + 1) * 4 + e];
  }

  // A per-thread source: element (rr, k4..k4+3) for all 4 e
  const int rr = t >> 3;                // 0..31
  const int k4 = (t & 7) * 4;           // 0,4,..,28
  const float* gA = A + (long)(i0 + rr) * N_NODES + koff + k4;
  // H store offset with k-group swizzle p = (g + (row>>1)) & 3
  const int hoff = rr * 32 + (((k4 >> 3) + (rr >> 1)) & 3) * 8 + (k4 & 7);

  // B staging: wave w stages plane w (cl = w>>1, hl = w&1), 8 issues/chunk
  const int kc_st = (((lane & 3) - ((lane >> 3) & 3)) & 3) * 8;
  const _Float16* gB = ((w & 1) ? BL : BH)
                     + ((long)(zz * 2 + (w >> 1)) * 128 + (lane >> 2)) * (long)N_NODES
                     + koff + kc_st;

  // MFMA fragment offsets
  const int wm = w >> 1, wn = w & 1;
  const int fr = lane & 15;
  const int fq = lane >> 4;
  const int fkz = ((fq + (fr >> 1)) & 3) * 8;
  const int aoff = (wm * 16 + fr) * 32 + fkz;
  const int boff = (wn * 64 + fr) * 32 + fkz;

  floatx4 acc[2][4];
  #pragma unroll
  for (int i = 0; i < 2; ++i)
    #pragma unroll
    for (int j = 0; j < 4; ++j) {
      floatx4 zz4 = {0.f, 0.f, 0.f, 0.f};
      acc[i][j] = zz4;
    }

  const int NKI = 16;
  for (int kt = 0; kt < NKI; ++kt) {
    // issue A loads (regs) and B stage (LDS) for THIS chunk up front;
    // B gloads stay outstanding until the mid-barrier drains vmcnt.
    float4 a0 = *(const float4*)(gA + kt * 32);
    float4 a1 = *(const float4*)(gA + NNE + kt * 32);
    float4 a2 = *(const float4*)(gA + 2 * NNE + kt * 32);
    float4 a3 = *(const float4*)(gA + 3 * NNE + kt * 32);
    {
      _Float16* lb = &Bs[w][0];
      const _Float16* g = gB + kt * 32;
      #pragma unroll
      for (int q = 0; q < 8; ++q)
        async_cp16(g + (long)q * (16L * N_NODES), lb + q * 512);
    }
    // mix + split -> Hs
    {
      float av0[4] = {a0.x, a0.y, a0.z, a0.w};
      float av1[4] = {a1.x, a1.y, a1.z, a1.w};
      float av2[4] = {a2.x, a2.y, a2.z, a2.w};
      float av3[4] = {a3.x, a3.y, a3.z, a3.w};
      half4_t h0, l0, h1, l1;
      #pragma unroll
      for (int d = 0; d < 4; ++d) {
        float o = wv0[0] * av0[d] + wv0[1] * av1[d] + wv0[2] * av2[d] + wv0[3] * av3[d];
        _Float16 hh = (_Float16)o;
        h0[d] = hh; l0[d] = (_Float16)(o - (float)hh);
        float u = wv1[0] * av0[d] + wv1[1] * av1[d] + wv1[2] * av2[d] + wv1[3] * av3[d];
        _Float16 uh = (_Float16)u;
        h1[d] = uh; l1[d] = (_Float16)(u - (float)uh);
      }
      *(half4_t*)&Hs[0][hoff] = h0;
      *(half4_t*)&Hs[1][hoff] = l0;
      *(half4_t*)&Hs[2][hoff] = h1;
      *(half4_t*)&Hs[3][hoff] = l1;
    }
    __syncthreads();   // Hs visible; drains B gloads (vmcnt 0) + lgkm
    #pragma unroll
    for (int cl = 0; cl < 2; ++cl) {
      half8_t ah = *(const half8_t*)&Hs[cl * 2 + 0][aoff];
      half8_t al = *(const half8_t*)&Hs[cl * 2 + 1][aoff];
      #pragma unroll
      for (int nt = 0; nt < 4; ++nt) {
        half8_t bh = *(const half8_t*)&Bs[cl * 2 + 0][boff + nt * 512];
        half8_t bl = *(const half8_t*)&Bs[cl * 2 + 1][boff + nt * 512];
        acc[cl][nt] = __builtin_amdgcn_mfma_f32_16x16x32_f16(ah, bh, acc[cl][nt], 0, 0, 0);
        acc[cl][nt] = __builtin_amdgcn_mfma_f32_16x16x32_f16(al, bh, acc[cl][nt], 0, 0, 0);
        acc[cl][nt] = __builtin_amdgcn_mfma_f32_16x16x32_f16(ah, bl, acc[cl][nt], 0, 0, 0);
      }
    }
    __syncthreads();   // everyone done reading Hs/Bs before next overwrite
  }

  const int er = fq * 4;
  const int ec = lane & 15;
  #pragma unroll
  for (int cl = 0; cl < 2; ++cl) {
    float* Cb = C + ((long)(blockIdx.z * 4 + zz * 2 + cl) * N_NODES + i0 + wm * 16) * 128;
    #pragma unroll
    for (int nt = 0; nt < 4; ++nt) {
      const int f = wn * 64 + nt * 16 + ec;
      #pragma unroll
      for (int r = 0; r < 4; ++r)
        Cb[(long)(er + r) * 128 + f] = acc[cl][nt][r];
    }
  }
}

// -- T'[z][f][j] = split( (sum_kc P[kc][z][j][f]) * s(cn_in[z][f]) ) --------
__global__ __launch_bounds__(256)
void combineT_k(const float* __restrict__ P, int nc,
                const float* __restrict__ cn_in, float* __restrict__ cn_out,
                _Float16* __restrict__ TH, _Float16* __restrict__ TL) {
  __shared__ _Float16 sh[32][33], sl[32][33];
  __shared__ float red[8][32];
  const int t = threadIdx.x;
  const int z = blockIdx.z;
  const int j0 = blockIdx.x * 32, f0 = blockIdx.y * 32;
  const int r0 = t >> 5, col = t & 31;
  const float s = colscale_from(cn_in[(long)z * 128 + f0 + col]);
  const long step = (long)nc * N_NODES * 128;
  float part = 0.f;
  #pragma unroll
  for (int m = 0; m < 4; ++m) {
    long idx = ((long)z * N_NODES + j0 + r0 + 8 * m) * 128 + f0 + col;
    float v = ((P[idx] + P[idx + step]) + (P[idx + 2 * step] + P[idx + 3 * step])) * s;
    _Float16 h = (_Float16)v;
    sh[r0 + 8 * m][col] = h;
    sl[r0 + 8 * m][col] = (_Float16)(v - (float)h);
    part += fabsf(v);
  }
  if (cn_out) red[r0][col] = part;
  __syncthreads();
  if (cn_out && t < 32) {
    float ss = 0.f;
    #pragma unroll
    for (int q = 0; q < 8; ++q) ss += red[q][t];
    atomicAdd(&cn_out[(long)z * 128 + f0 + t], ss);
  }
  const int rr = t >> 3, cq = (t & 7) * 4;
  half4_t oh, ol;
  #pragma unroll
  for (int d = 0; d < 4; ++d) { oh[d] = sh[cq + d][rr]; ol[d] = sl[cq + d][rr]; }
  long ob = (long)z * 128 * N_NODES + (long)(f0 + rr) * N_NODES + j0 + cq;
  *(half4_t*)(TH + ob) = oh;
  *(half4_t*)(TL + ob) = ol;
}

// --- out[i][c*128+f] = relu( d*( T2sum * 2^(i0+i1-33) + supd ) + b ) -------
__global__ __launch_bounds__(256)
void final_k(const float4* __restrict__ T2, const float4* __restrict__ supd,
             const float* __restrict__ dvec, const float* __restrict__ cn0,
             const float* __restrict__ cn1, const float* __restrict__ bias,
             float* __restrict__ out) {
  const int t = threadIdx.x;
  const int z = blockIdx.y;
  const int idx = blockIdx.x * 256 + t;
  const int i = idx >> 5;
  const int fq = (idx & 31) * 4;
  const long step4 = 4L * N_NODES * 32;
  long b4 = (long)z * N_NODES * 32 + idx;
  float4 s0 = T2[b4];
  float4 s1 = T2[b4 + step4];
  float4 s2 = T2[b4 + 2 * step4];
  float4 s3 = T2[b4 + 3 * step4];
  float4 sp = supd[(long)z * N_NODES * 32 + idx];
  const float dn = dvec[(long)z * N_NODES + i];
  float inv[4];
  #pragma unroll
  for (int d = 0; d < 4; ++d) {
    int i0 = ilogbf(fmaxf(cn0[(long)z * 128 + fq + d], 1e-37f));
    int i1 = ilogbf(fmaxf(cn1[(long)z * 128 + fq + d], 1e-37f));
    inv[d] = exp2f((float)(i0 + i1 - 33));
  }
  float4 o;
  o.x = fmaxf(dn * (((s0.x + s1.x) + (s2.x + s3.x)) * inv[0] + sp.x) + bias[fq + 0], 0.f);
  o.y = fmaxf(dn * (((s0.y + s1.y) + (s2.y + s3.y)) * inv[1] + sp.y) + bias[fq + 1], 0.f);
  o.z = fmaxf(dn * (((s0.z + s1.z) + (s2.z + s3.z)) * inv[2] + sp.z) + bias[fq + 2], 0.f);
  o.w = fmaxf(dn * (((s0.w + s1.w) + (s2.w + s3.w)) * inv[3] + sp.w) + bias[fq + 3], 0.f);
  *(float4*)(out + (long)i * 512 + z * 128 + fq) = o;
}

extern "C" void kernel_launch(void* const* d_in, const int* in_sizes, int n_in,
                              void* d_out, int out_size, void* d_ws, size_t ws_size,
                              hipStream_t stream) {
  const float* A  = (const float*)d_in[0];
  const float* X  = (const float*)d_in[1];
  const float* w1 = (const float*)d_in[2];
  const float* w2 = (const float*)d_in[3];
  const float* w3 = (const float*)d_in[4];
  const float* gw = (const float*)d_in[5];
  const float* gb = (const float*)d_in[6];
  float* out = (float*)d_out;

  // ---- workspace layout (floats first, then f16 arena; all 16B aligned) ----
  float* ws   = (float*)d_ws;
  float* fw   = ws;                         // 64
  float* rc   = fw + 64;                    // 4*2048
  float* v1   = rc + 4 * N_NODES;           // 4*2048
  float* deg  = v1 + 4 * N_NODES;           // 4*2048
  float* dvec = deg + 4 * N_NODES;          // 4*2048
  float* sup  = dvec + 4 * N_NODES;         // 2048*128
  float* cn0  = sup + (long)N_NODES * 128;  // 512
  float* cn1  = cn0 + 512;                  // 512
  float* supd = cn1 + 512;                  // 4*2048*128
  float* Mtmp = supd + 4L * N_NODES * 128;  // [4kc][4ch][2048][128]
  _Float16* arena = (_Float16*)(Mtmp + 16L * N_NODES * 128);
  _Float16* VTH = arena;                    // [4][128][2048]
  _Float16* VTL = VTH + 4L * 128 * N_NODES;
  _Float16* T0H = VTL + 4L * 128 * N_NODES;
  _Float16* T0L = T0H + 4L * 128 * N_NODES;
  _Float16* T1H = T0L + 4L * 128 * N_NODES;
  _Float16* T1L = T1H + 4L * 128 * N_NODES;

  // ---- prework ----
  softmax3_zero_k<<<1, 256, 0, stream>>>(w1, w2, w3, fw, cn0);   // zeroes cn0+cn1
  support_k<<<N_NODES, 128, 0, stream>>>(X, gw, sup);
  // deg chain: rc = fw3-mix of rowsum(A_e); v1 = Hb@rc; deg = Ha@v1
  rc_from_A_k<<<N_NODES / 4, 256, 0, stream>>>(A, fw, rc);
  matvecA_k<<<N_NODES / 4, 256, 0, stream>>>(A, fw, 16, rc, v1);
  matvecA_k<<<N_NODES / 4, 256, 0, stream>>>(A, fw, 0, v1, deg);
  // supd = d .* support ; VT = (supd*2^13)^T split ; cn0 col 1-norms
  transposeV_k<<<dim3(64, 4, 4), 256, 0, stream>>>(sup, deg, dvec, supd,
                                                   VTH, VTL, cn0);
  // T0 = Hc @ VT   (mix-on-the-fly from A, fw offset 32)
  gemm_mix_k<<<dim3(2, 64, 4), 256, 0, stream>>>(A, fw, 32, VTH, VTL, Mtmp);
  combineT_k<<<dim3(64, 4, 4), 256, 0, stream>>>(Mtmp, 4, cn0, cn1, T0H, T0L);
  // T1 = Hb @ T0'  (fw offset 16)
  gemm_mix_k<<<dim3(2, 64, 4), 256, 0, stream>>>(A, fw, 16, T0H, T0L, Mtmp);
  combineT_k<<<dim3(64, 4, 4), 256, 0, stream>>>(Mtmp, 4, cn1, nullptr, T1H, T1L);
  // T2 = Ha @ T1'  (fw offset 0, fp32 partials)
  gemm_mix_k<<<dim3(2, 64, 4), 256, 0, stream>>>(A, fw, 0, T1H, T1L, Mtmp);
  // out = relu( d*(T2*inv + supd) + b )
  final_k<<<dim3(256, 4), 256, 0, stream>>>((const float4*)Mtmp,
                                            (const float4*)supd, dvec,
                                            cn0, cn1, gb, out);
}